// Round 4
// baseline (54.277 us; speedup 1.0000x reference)
//
#include <hip/hip_runtime.h>
#include <hip/hip_bf16.h>
#include <stdint.h>

typedef __attribute__((ext_vector_type(8))) __bf16 bf16x8;
typedef __attribute__((ext_vector_type(4))) float f32x4;

static constexpr int Bb = 32, Ss = 512, Dd = 1024, Rr = 256;

__device__ __forceinline__ void gload_lds16(const void* g, void* l) {
  __builtin_amdgcn_global_load_lds(
      (const __attribute__((address_space(1))) void*)g,
      (__attribute__((address_space(3))) void*)l, 16, 0, 0);
}

// ---- prep: Bt[512][1024] bf16. rows 0-255 = L^T, rows 256-511 = R ----------
__global__ __launch_bounds__(256) void prep_kernel(
    const float* __restrict__ L, const float* __restrict__ R,
    __bf16* __restrict__ Bt) {
  int i = blockIdx.x * 256 + threadIdx.x;  // 0 .. 512*1024-1 exactly
  int n = i >> 10;
  int d = i & (Dd - 1);
  float v = (n < Rr) ? L[d * Rr + n] : R[(size_t)(n - Rr) * Dd + d];
  Bt[i] = (__bf16)v;
}

// ---- stage 1: C[16384,512] = batch_f32[16384,1024] x Bt[512,1024]^T --------
// BM=128 BN=256 BK=32, 512 threads (8 waves, 64x64 each), 256 blocks = 1/CU.
// Double-buffered LDS 48KB. Counted vmcnt + raw s_barrier (T3/T4): next
// tile's loads stay in flight across the barrier; no vmcnt(0) in main loop.
// A: reg-staged fp32 -> cvt -> swizzled ds_write (bf16 in LDS).
// B: global_load_lds, pre-swizzled source (rule 21). Swizzle: g^((row>>1)&3).
__global__ __launch_bounds__(512, 2) void proj_gemm(
    const float* __restrict__ batch,
    const __bf16* __restrict__ Bt,   // [512][1024]
    __bf16* __restrict__ outL,       // [16384][256]
    __bf16* __restrict__ outR) {     // [16384][256]
  // XCD-chunked swizzle: 256 blocks, 8 XCDs -> 32-block chunks; nt-siblings
  // of one mt are consecutive -> co-XCD for A-panel L2 reuse.
  const int s = (blockIdx.x & 7) * 32 + (blockIdx.x >> 3);
  const int mt = s >> 1;  // 0..127
  const int nt = s & 1;   // 0..1
  const int m0 = mt * 128, n0 = nt * 256;

  __shared__ __align__(16) char smem[49152];
  // A bf16 [128][32]: buf b at b*8192 (8KB each)
  // B bf16 [256][32]: buf b at 16384 + b*16384 (16KB each)

  const int t = threadIdx.x;
  const int lane = t & 63;
  const int wave = t >> 6;
  const int wr = wave >> 2, wc = wave & 3;  // 2 x 4 waves, 64x64 tiles

  f32x4 acc[4][4] = {};
  f32x4 areg0, areg1;

  // A: thread t covers row=t>>2 (0..127), granule g=t&3 (8 fp32 each)
  const int arow = t >> 2, ag = t & 3;
  const int ags = ag ^ ((arow >> 1) & 3);  // swizzled LDS slot

  auto issueA = [&](int k0) {
    const float* src = batch + (size_t)(m0 + arow) * Dd + k0 + ag * 8;
    areg0 = *(const f32x4*)src;
    areg1 = *(const f32x4*)(src + 4);
  };
  auto writeA = [&](int buf) {
    bf16x8 v;
    v[0] = (__bf16)areg0[0]; v[1] = (__bf16)areg0[1];
    v[2] = (__bf16)areg0[2]; v[3] = (__bf16)areg0[3];
    v[4] = (__bf16)areg1[0]; v[5] = (__bf16)areg1[1];
    v[6] = (__bf16)areg1[2]; v[7] = (__bf16)areg1[3];
    *(bf16x8*)(smem + buf * 8192 + (arow * 4 + ags) * 16) = v;
  };
  auto stageB = [&](int buf, int k0) {
#pragma unroll
    for (int p = 0; p < 2; ++p) {
      int e = p * 512 + t;
      int row = e >> 2, g = e & 3;
      int gs = g ^ ((row >> 1) & 3);  // inverse-swizzled SOURCE, linear dest
      gload_lds16(Bt + (size_t)(n0 + row) * Dd + k0 + gs * 8,
                  smem + 16384 + buf * 16384 + e * 16);
    }
  };
  auto compute = [&](int buf) {
    const char* Ab = smem + buf * 8192;
    const char* Bb = smem + 16384 + buf * 16384;
    bf16x8 a[4], b[4];
    const int g = lane >> 4;  // k-granule 0..3
#pragma unroll
    for (int m = 0; m < 4; ++m) {
      int row = wr * 64 + m * 16 + (lane & 15);
      a[m] = *(const bf16x8*)(Ab + (row * 4 + (g ^ ((row >> 1) & 3))) * 16);
    }
#pragma unroll
    for (int n = 0; n < 4; ++n) {
      int row = wc * 64 + n * 16 + (lane & 15);
      b[n] = *(const bf16x8*)(Bb + (row * 4 + (g ^ ((row >> 1) & 3))) * 16);
    }
#pragma unroll
    for (int m = 0; m < 4; ++m)
#pragma unroll
      for (int n = 0; n < 4; ++n)
        acc[m][n] = __builtin_amdgcn_mfma_f32_16x16x32_bf16(a[m], b[n],
                                                            acc[m][n], 0, 0, 0);
  };

  // prologue: tile 0 fully staged (one-time latency hit)
  issueA(0);
  stageB(0, 0);
  writeA(0);  // compiler emits counted vmcnt(2) for areg dep
  int cur = 0;
  for (int it = 0; it < 32; ++it) {
    if (it < 31) {
      issueA(it * 32 + 32);
      stageB(cur ^ 1, it * 32 + 32);
      // drain THIS tile's B loads only; next tile's 4 ops stay in flight
      asm volatile("s_waitcnt vmcnt(4)" ::: "memory");
    } else {
      asm volatile("s_waitcnt vmcnt(0)" ::: "memory");
    }
    __builtin_amdgcn_s_barrier();
    compute(cur);
    if (it < 31) writeA(cur ^ 1);  // counted vmcnt(2) auto for areg dep
    asm volatile("s_waitcnt lgkmcnt(0)" ::: "memory");
    __builtin_amdgcn_s_barrier();
    cur ^= 1;
  }

  // epilogue: nt selects the output half directly (BN=256)
  __bf16* out = nt ? outR : outL;
  const int col = lane & 15, rgrp = lane >> 4;
#pragma unroll
  for (int m = 0; m < 4; ++m) {
    int r0 = m0 + wr * 64 + m * 16 + rgrp * 4;
#pragma unroll
    for (int n = 0; n < 4; ++n) {
      int c = wc * 64 + n * 16 + col;
#pragma unroll
      for (int i = 0; i < 4; ++i)
        out[(size_t)(r0 + i) * Rr + c] = (__bf16)acc[m][n][i];
    }
  }
}

// ---- stage 2: logits[b] = left[b] @ right[b]^T + bias ----------------------
// Per batch: C[512,512] f32 = A[512,256] x Bt[512,256], both bf16 K-contig.
// 64x128 tile, BK=64, single-buffer 24KB, swizzled. 1024 blocks (4/CU).
__global__ __launch_bounds__(256, 4) void score_gemm(
    const __bf16* __restrict__ left,
    const __bf16* __restrict__ right,
    const float* __restrict__ biasp,
    float* __restrict__ out) {
  const int nt = blockIdx.x;  // 0..3
  const int mt = blockIdx.y;  // 0..7
  const int bz = blockIdx.z;  // 0..31
  const __bf16* A = left + (size_t)bz * Ss * Rr;
  const __bf16* B = right + (size_t)bz * Ss * Rr;
  float* O = out + (size_t)bz * Ss * Ss;
  const int m0 = mt * 64, n0 = nt * 128;

  __shared__ __align__(16) char smem[24576];
  // A bf16 [64][64] @ 0 (8KB), B bf16 [128][64] @ 8192 (16KB)

  const int t = threadIdx.x;
  const int lane = t & 63;
  const int wave = t >> 6;
  const int wr = wave >> 1, wc = wave & 1;

  f32x4 acc[2][4] = {};

  for (int it = 0; it < 4; ++it) {
    const int k0 = it * 64;
    __syncthreads();
#pragma unroll
    for (int q = 0; q < 2; ++q) {  // A: 512 granules
      int e = q * 256 + t;
      int row = e >> 3, g = e & 7;
      int gsrc = g ^ (row & 7);
      gload_lds16(A + (size_t)(m0 + row) * Rr + k0 + gsrc * 8, smem + e * 16);
    }
#pragma unroll
    for (int q = 0; q < 4; ++q) {  // B: 1024 granules
      int e = q * 256 + t;
      int row = e >> 3, g = e & 7;
      int gsrc = g ^ (row & 7);
      gload_lds16(B + (size_t)(n0 + row) * Rr + k0 + gsrc * 8,
                  smem + 8192 + e * 16);
    }
    __syncthreads();

#pragma unroll
    for (int kk = 0; kk < 2; ++kk) {
      bf16x8 a[2], b[4];
#pragma unroll
      for (int m = 0; m < 2; ++m) {
        int row = wr * 32 + m * 16 + (lane & 15);
        int g = kk * 4 + (lane >> 4);
        a[m] = *(const bf16x8*)(smem + (row * 8 + (g ^ (row & 7))) * 16);
      }
#pragma unroll
      for (int n = 0; n < 4; ++n) {
        int row = wc * 64 + n * 16 + (lane & 15);
        int g = kk * 4 + (lane >> 4);
        b[n] = *(const bf16x8*)(smem + 8192 +
                                (row * 8 + (g ^ (row & 7))) * 16);
      }
#pragma unroll
      for (int m = 0; m < 2; ++m)
#pragma unroll
        for (int n = 0; n < 4; ++n)
          acc[m][n] = __builtin_amdgcn_mfma_f32_16x16x32_bf16(a[m], b[n],
                                                              acc[m][n], 0, 0, 0);
    }
  }

  const float bias = *biasp;
  const int col = lane & 15, rgrp = lane >> 4;
#pragma unroll
  for (int m = 0; m < 2; ++m) {
    int r0 = m0 + wr * 32 + m * 16 + rgrp * 4;
#pragma unroll
    for (int n = 0; n < 4; ++n) {
      int c = n0 + wc * 64 + n * 16 + col;
#pragma unroll
      for (int i = 0; i < 4; ++i)
        O[(size_t)(r0 + i) * Ss + c] = acc[m][n][i] + bias;
    }
  }
}

extern "C" void kernel_launch(void* const* d_in, const int* in_sizes, int n_in,
                              void* d_out, int out_size, void* d_ws,
                              size_t ws_size, hipStream_t stream) {
  const float* batch = (const float*)d_in[0];  // [32][512][1024]
  const float* projL = (const float*)d_in[1];  // [1024][256]
  const float* projR = (const float*)d_in[2];  // [256][1024]
  const float* bias = (const float*)d_in[3];   // [1]
  float* out = (float*)d_out;                  // [32][512][512]

  char* ws = (char*)d_ws;
  __bf16* left = (__bf16*)(ws);                 // 8,388,608 B [16384][256]
  __bf16* right = (__bf16*)(ws + 8388608);      // 8,388,608 B [16384][256]
  __bf16* Btc = (__bf16*)(ws + 16777216);       // 1,048,576 B [512][1024]

  prep_kernel<<<dim3(2048), dim3(256), 0, stream>>>(projL, projR, Btc);
  proj_gemm<<<dim3(256), dim3(512), 0, stream>>>(batch, Btc, left, right);
  score_gemm<<<dim3(4, 8, 32), dim3(256), 0, stream>>>(left, right, bias, out);
}

// Round 5
// 51.727 us; speedup vs baseline: 1.0493x; 1.0493x over previous
//
#include <hip/hip_runtime.h>
#include <hip/hip_bf16.h>
#include <stdint.h>

typedef __attribute__((ext_vector_type(8))) __bf16 bf16x8;
typedef __attribute__((ext_vector_type(4))) float f32x4;

static constexpr int Bb = 32, Ss = 512, Dd = 1024, Rr = 256;

__device__ __forceinline__ void gload_lds16(const void* g, void* l) {
  __builtin_amdgcn_global_load_lds(
      (const __attribute__((address_space(1))) void*)g,
      (__attribute__((address_space(3))) void*)l, 16, 0, 0);
}

// ---- prep: Bt[512][1024] bf16. rows 0-255 = L^T, rows 256-511 = R ----------
__global__ __launch_bounds__(256) void prep_kernel(
    const float* __restrict__ L, const float* __restrict__ R,
    __bf16* __restrict__ Bt) {
  int i = blockIdx.x * 256 + threadIdx.x;  // 0 .. 512*1024-1 exactly
  int n = i >> 10;
  int d = i & (Dd - 1);
  float v = (n < Rr) ? L[d * Rr + n] : R[(size_t)(n - Rr) * Dd + d];
  Bt[i] = (__bf16)v;
}

// ---- stage 1: C[16384,512] = batch_f32[16384,1024] x Bt[512,1024]^T --------
// T3-minimum 2-phase: BM=256 BN=128 BK=64, 512 thr (8 waves, 4Mx2N, 64x64
// each), grid 256 = 1 block/CU, dbuf LDS 96KB, ONE barrier per K-tile.
// Per tile: {issue A-regs + B gload_lds for t+1} -> compute(t) -> cvt+writeA
// (t+1) -> vmcnt(0)+lgkmcnt(0) -> s_barrier. Swizzle g^=(row&7) both sides.
__global__ __launch_bounds__(512, 2) void proj_gemm(
    const float* __restrict__ batch,
    const __bf16* __restrict__ Bt,   // [512][1024]
    __bf16* __restrict__ outL,       // [16384][256]
    __bf16* __restrict__ outR) {     // [16384][256]
  // XCD-chunked: 256 blocks, chunks of 32; nt-siblings of one mt co-XCD.
  const int s = ((blockIdx.x & 7) << 5) + (blockIdx.x >> 3);
  const int mt = s >> 2;  // 0..63
  const int nt = s & 3;   // 0..3
  const int m0 = mt * 256, n0 = nt * 128;

  __shared__ __align__(16) char smem[98304];
  // A bf16 [256][64]: buf b at b*32768 (32KB each)
  // B bf16 [128][64]: buf b at 65536 + b*16384 (16KB each)

  const int t = threadIdx.x;
  const int lane = t & 63;
  const int wave = t >> 6;
  const int wr = wave >> 1, wc = wave & 1;  // 4M x 2N waves, 64x64 tiles

  f32x4 acc[4][4] = {};
  f32x4 areg[8];  // 4 granules x 2 f32x4, in flight across compute

  // A staging coords: 4 granules/thread, e = q*512+t, row=e>>3, g=e&7
  auto issueA = [&](int k0) {
#pragma unroll
    for (int q = 0; q < 4; ++q) {
      int e = q * 512 + t;
      int row = e >> 3, g = e & 7;
      const float* src = batch + (size_t)(m0 + row) * Dd + k0 + g * 8;
      areg[2 * q] = *(const f32x4*)src;
      areg[2 * q + 1] = *(const f32x4*)(src + 4);
    }
  };
  auto writeA = [&](int buf) {
    char* Ab = smem + buf * 32768;
#pragma unroll
    for (int q = 0; q < 4; ++q) {
      int e = q * 512 + t;
      int row = e >> 3, g = e & 7;
      int gs = g ^ (row & 7);
      f32x4 f0 = areg[2 * q], f1 = areg[2 * q + 1];
      bf16x8 v;
      v[0] = (__bf16)f0[0]; v[1] = (__bf16)f0[1];
      v[2] = (__bf16)f0[2]; v[3] = (__bf16)f0[3];
      v[4] = (__bf16)f1[0]; v[5] = (__bf16)f1[1];
      v[6] = (__bf16)f1[2]; v[7] = (__bf16)f1[3];
      *(bf16x8*)(Ab + (row * 8 + gs) * 16) = v;
    }
  };
  auto stageB = [&](int buf, int k0) {
    char* Bbuf = smem + 65536 + buf * 16384;
#pragma unroll
    for (int p = 0; p < 2; ++p) {
      int e = p * 512 + t;
      int row = e >> 3, g = e & 7;
      int gs = g ^ (row & 7);  // inverse-swizzled SOURCE, linear LDS dest
      gload_lds16(Bt + (size_t)(n0 + row) * Dd + k0 + gs * 8,
                  Bbuf + e * 16);
    }
  };
  auto compute = [&](int buf) {
    const char* Ab = smem + buf * 32768;
    const char* Bbuf = smem + 65536 + buf * 16384;
#pragma unroll
    for (int kk = 0; kk < 2; ++kk) {
      const int g = kk * 4 + (lane >> 4);
      bf16x8 a[4], b[4];
#pragma unroll
      for (int m = 0; m < 4; ++m) {
        int row = wr * 64 + m * 16 + (lane & 15);
        a[m] = *(const bf16x8*)(Ab + (row * 8 + (g ^ (row & 7))) * 16);
      }
#pragma unroll
      for (int n = 0; n < 4; ++n) {
        int row = wc * 64 + n * 16 + (lane & 15);
        b[n] = *(const bf16x8*)(Bbuf + (row * 8 + (g ^ (row & 7))) * 16);
      }
#pragma unroll
      for (int m = 0; m < 4; ++m)
#pragma unroll
        for (int n = 0; n < 4; ++n)
          acc[m][n] = __builtin_amdgcn_mfma_f32_16x16x32_bf16(a[m], b[n],
                                                              acc[m][n], 0, 0, 0);
    }
  };

  // prologue: stage tile 0 into buf 0
  issueA(0);
  stageB(0, 0);
  writeA(0);  // compiler inserts counted vmcnt for areg dep
  asm volatile("s_waitcnt vmcnt(0)" ::: "memory");   // B DMA landed
  asm volatile("s_waitcnt lgkmcnt(0)" ::: "memory"); // A ds_writes done
  __builtin_amdgcn_s_barrier();

  for (int tt = 0; tt < 16; ++tt) {
    const int buf = tt & 1;
    if (tt < 15) {
      issueA(tt * 64 + 64);       // 8 global loads, in flight under compute
      stageB(buf ^ 1, tt * 64 + 64);  // 2 gload_lds, in flight under compute
    }
    compute(buf);                 // 16 ds_read_b128 + 32 MFMA
    if (tt < 15) {
      writeA(buf ^ 1);            // counted vmcnt for areg, cvt + 4 ds_write
      asm volatile("s_waitcnt vmcnt(0)" ::: "memory");   // drain 2 B DMAs
      asm volatile("s_waitcnt lgkmcnt(0)" ::: "memory"); // drain ds_writes
      __builtin_amdgcn_s_barrier();
    }
  }

  // epilogue: n-range lies wholly in L (n0<256) or R half
  __bf16* out = (n0 < Rr) ? outL : outR;
  const int cb = n0 & (Rr - 1);
  const int col = lane & 15, rgrp = lane >> 4;
#pragma unroll
  for (int m = 0; m < 4; ++m) {
    int r0 = m0 + wr * 64 + m * 16 + rgrp * 4;
#pragma unroll
    for (int n = 0; n < 4; ++n) {
      int c = cb + wc * 64 + n * 16 + col;
#pragma unroll
      for (int i = 0; i < 4; ++i)
        out[(size_t)(r0 + i) * Rr + c] = (__bf16)acc[m][n][i];
    }
  }
}

// ---- stage 2: logits[b] = left[b] @ right[b]^T + bias ----------------------
// Per batch: C[512,512] f32 = A[512,256] x Bt[512,256], both bf16 K-contig.
// 64x128 tile, BK=64, single-buffer 24KB, swizzled. 1024 blocks (4/CU).
__global__ __launch_bounds__(256, 4) void score_gemm(
    const __bf16* __restrict__ left,
    const __bf16* __restrict__ right,
    const float* __restrict__ biasp,
    float* __restrict__ out) {
  const int nt = blockIdx.x;  // 0..3
  const int mt = blockIdx.y;  // 0..7
  const int bz = blockIdx.z;  // 0..31
  const __bf16* A = left + (size_t)bz * Ss * Rr;
  const __bf16* B = right + (size_t)bz * Ss * Rr;
  float* O = out + (size_t)bz * Ss * Ss;
  const int m0 = mt * 64, n0 = nt * 128;

  __shared__ __align__(16) char smem[24576];
  // A bf16 [64][64] @ 0 (8KB), B bf16 [128][64] @ 8192 (16KB)

  const int t = threadIdx.x;
  const int lane = t & 63;
  const int wave = t >> 6;
  const int wr = wave >> 1, wc = wave & 1;

  f32x4 acc[2][4] = {};

  for (int it = 0; it < 4; ++it) {
    const int k0 = it * 64;
    __syncthreads();
#pragma unroll
    for (int q = 0; q < 2; ++q) {  // A: 512 granules
      int e = q * 256 + t;
      int row = e >> 3, g = e & 7;
      int gsrc = g ^ (row & 7);
      gload_lds16(A + (size_t)(m0 + row) * Rr + k0 + gsrc * 8, smem + e * 16);
    }
#pragma unroll
    for (int q = 0; q < 4; ++q) {  // B: 1024 granules
      int e = q * 256 + t;
      int row = e >> 3, g = e & 7;
      int gsrc = g ^ (row & 7);
      gload_lds16(B + (size_t)(n0 + row) * Rr + k0 + gsrc * 8,
                  smem + 8192 + e * 16);
    }
    __syncthreads();

#pragma unroll
    for (int kk = 0; kk < 2; ++kk) {
      bf16x8 a[2], b[4];
#pragma unroll
      for (int m = 0; m < 2; ++m) {
        int row = wr * 32 + m * 16 + (lane & 15);
        int g = kk * 4 + (lane >> 4);
        a[m] = *(const bf16x8*)(smem + (row * 8 + (g ^ (row & 7))) * 16);
      }
#pragma unroll
      for (int n = 0; n < 4; ++n) {
        int row = wc * 64 + n * 16 + (lane & 15);
        int g = kk * 4 + (lane >> 4);
        b[n] = *(const bf16x8*)(smem + 8192 +
                                (row * 8 + (g ^ (row & 7))) * 16);
      }
#pragma unroll
      for (int m = 0; m < 2; ++m)
#pragma unroll
        for (int n = 0; n < 4; ++n)
          acc[m][n] = __builtin_amdgcn_mfma_f32_16x16x32_bf16(a[m], b[n],
                                                              acc[m][n], 0, 0, 0);
    }
  }

  const float bias = *biasp;
  const int col = lane & 15, rgrp = lane >> 4;
#pragma unroll
  for (int m = 0; m < 2; ++m) {
    int r0 = m0 + wr * 32 + m * 16 + rgrp * 4;
#pragma unroll
    for (int n = 0; n < 4; ++n) {
      int c = n0 + wc * 64 + n * 16 + col;
#pragma unroll
      for (int i = 0; i < 4; ++i)
        O[(size_t)(r0 + i) * Ss + c] = acc[m][n][i] + bias;
    }
  }
}

extern "C" void kernel_launch(void* const* d_in, const int* in_sizes, int n_in,
                              void* d_out, int out_size, void* d_ws,
                              size_t ws_size, hipStream_t stream) {
  const float* batch = (const float*)d_in[0];  // [32][512][1024]
  const float* projL = (const float*)d_in[1];  // [1024][256]
  const float* projR = (const float*)d_in[2];  // [256][1024]
  const float* bias = (const float*)d_in[3];   // [1]
  float* out = (float*)d_out;                  // [32][512][512]

  char* ws = (char*)d_ws;
  __bf16* left = (__bf16*)(ws);                 // 8,388,608 B [16384][256]
  __bf16* right = (__bf16*)(ws + 8388608);      // 8,388,608 B [16384][256]
  __bf16* Btc = (__bf16*)(ws + 16777216);       // 1,048,576 B [512][1024]

  prep_kernel<<<dim3(2048), dim3(256), 0, stream>>>(projL, projR, Btc);
  proj_gemm<<<dim3(256), dim3(512), 0, stream>>>(batch, Btc, left, right);
  score_gemm<<<dim3(4, 8, 32), dim3(256), 0, stream>>>(left, right, bias, out);
}

// Round 6
// 49.679 us; speedup vs baseline: 1.0926x; 1.0412x over previous
//
#include <hip/hip_runtime.h>
#include <hip/hip_bf16.h>
#include <stdint.h>

typedef __attribute__((ext_vector_type(8))) __bf16 bf16x8;
typedef __attribute__((ext_vector_type(4))) float f32x4;

static constexpr int Bb = 32, Ss = 512, Dd = 1024, Rr = 256;

__device__ __forceinline__ void gload_lds16(const void* g, void* l) {
  __builtin_amdgcn_global_load_lds(
      (const __attribute__((address_space(1))) void*)g,
      (__attribute__((address_space(3))) void*)l, 16, 0, 0);
}

// ---- prep: Bt[512][1024] bf16. rows 0-255 = L^T, rows 256-511 = R ----------
__global__ __launch_bounds__(256) void prep_kernel(
    const float* __restrict__ L, const float* __restrict__ R,
    __bf16* __restrict__ Bt) {
  int i = blockIdx.x * 256 + threadIdx.x;  // 0 .. 512*1024-1 exactly
  int n = i >> 10;
  int d = i & (Dd - 1);
  float v = (n < Rr) ? L[d * Rr + n] : R[(size_t)(n - Rr) * Dd + d];
  Bt[i] = (__bf16)v;
}

// ---- stage 1: C[16384,512] = batch_f32[16384,1024] x Bt[512,1024]^T --------
// BN=512: full N per block -> each batch element read by EXACTLY ONE block
// (A traffic 64MB once, vs 256MB re-read in R1-R5). BM=64, BK=64, 512 thr
// (8 waves = 1Mx8N, 64x64 each), grid 256 = 1 blk/CU, dbuf LDS 144KB.
// One barrier per K-tile, counted vmcnt (T3/T4). Swizzle g^=(row&7) both
// sides (rule 21). A: fp32 reg-stage -> cvt -> swizzled ds_write.
__global__ __launch_bounds__(512, 1) void proj_gemm(
    const float* __restrict__ batch,
    const __bf16* __restrict__ Bt,   // [512][1024]
    __bf16* __restrict__ outL,       // [16384][256]
    __bf16* __restrict__ outR) {     // [16384][256]
  // chunked remap (bijective, 256 = 8*32) for HBM-page locality per XCD
  const int s = ((blockIdx.x & 7) << 5) + (blockIdx.x >> 3);
  const int m0 = s * 64;

  __shared__ __align__(16) char smem[147456];
  // A bf16 [64][64]:  buf b at b*8192           (8KB each)
  // B bf16 [512][64]: buf b at 16384 + b*65536  (64KB each)

  const int t = threadIdx.x;
  const int lane = t & 63;
  const int wave = t >> 6;  // 0..7 = N-position

  f32x4 acc[4][4] = {};
  f32x4 areg0, areg1;

  // A staging: 512 granules of 8 floats (64 rows x 8), one per thread
  const int arow = t >> 3, ag = t & 7;
  const int ags = ag ^ (arow & 7);

  auto issueA = [&](int k0) {
    const float* src = batch + (size_t)(m0 + arow) * Dd + k0 + ag * 8;
    areg0 = *(const f32x4*)src;
    areg1 = *(const f32x4*)(src + 4);
  };
  auto writeA = [&](int buf) {
    bf16x8 v;
    v[0] = (__bf16)areg0[0]; v[1] = (__bf16)areg0[1];
    v[2] = (__bf16)areg0[2]; v[3] = (__bf16)areg0[3];
    v[4] = (__bf16)areg1[0]; v[5] = (__bf16)areg1[1];
    v[6] = (__bf16)areg1[2]; v[7] = (__bf16)areg1[3];
    *(bf16x8*)(smem + buf * 8192 + (arow * 8 + ags) * 16) = v;
  };
  auto stageB = [&](int buf, int k0) {
    char* Bbuf = smem + 16384 + buf * 65536;
#pragma unroll
    for (int p = 0; p < 8; ++p) {
      int e = p * 512 + t;
      int row = e >> 3, g = e & 7;
      int gs = g ^ (row & 7);  // inverse-swizzled SOURCE, linear LDS dest
      gload_lds16(Bt + (size_t)row * Dd + k0 + gs * 8, Bbuf + e * 16);
    }
  };
  auto compute = [&](int buf) {
    const char* Ab = smem + buf * 8192;
    const char* Bbuf = smem + 16384 + buf * 65536;
#pragma unroll
    for (int kk = 0; kk < 2; ++kk) {
      const int g = kk * 4 + (lane >> 4);
      bf16x8 a[4], b[4];
#pragma unroll
      for (int m = 0; m < 4; ++m) {
        int row = m * 16 + (lane & 15);
        a[m] = *(const bf16x8*)(Ab + (row * 8 + (g ^ (row & 7))) * 16);
      }
#pragma unroll
      for (int n = 0; n < 4; ++n) {
        int row = wave * 64 + n * 16 + (lane & 15);
        b[n] = *(const bf16x8*)(Bbuf + (row * 8 + (g ^ (row & 7))) * 16);
      }
#pragma unroll
      for (int m = 0; m < 4; ++m)
#pragma unroll
        for (int n = 0; n < 4; ++n)
          acc[m][n] = __builtin_amdgcn_mfma_f32_16x16x32_bf16(a[m], b[n],
                                                              acc[m][n], 0, 0, 0);
    }
  };

  // prologue: tile 0 into buf 0 (A loads issued BEFORE B DMAs -> writeA's
  // compiler-counted vmcnt retires only the A loads)
  issueA(0);
  stageB(0, 0);
  writeA(0);
  asm volatile("s_waitcnt vmcnt(0)" ::: "memory");
  asm volatile("s_waitcnt lgkmcnt(0)" ::: "memory");
  __builtin_amdgcn_s_barrier();

  for (int tt = 0; tt < 16; ++tt) {
    const int buf = tt & 1;
    if (tt < 15) {
      issueA(tt * 64 + 64);           // 2 global loads, under compute
      stageB(buf ^ 1, tt * 64 + 64);  // 8 gload_lds, under compute
    }
    compute(buf);                     // 16 ds_read_b128 + 32 MFMA
    if (tt < 15) {
      writeA(buf ^ 1);                // counted vmcnt for areg only
      asm volatile("s_waitcnt vmcnt(0)" ::: "memory");   // drain B DMAs
      asm volatile("s_waitcnt lgkmcnt(0)" ::: "memory"); // drain ds_writes
      __builtin_amdgcn_s_barrier();
    }
  }

  // epilogue: wave 0-3 -> outL cols, wave 4-7 -> outR cols
  __bf16* out = (wave < 4) ? outL : outR;
  const int wcb = (wave & 3) * 64;
  const int col = lane & 15, rgrp = lane >> 4;
#pragma unroll
  for (int m = 0; m < 4; ++m) {
    int r0 = m0 + m * 16 + rgrp * 4;
#pragma unroll
    for (int n = 0; n < 4; ++n) {
      int c = wcb + n * 16 + col;
#pragma unroll
      for (int i = 0; i < 4; ++i)
        out[(size_t)(r0 + i) * Rr + c] = (__bf16)acc[m][n][i];
    }
  }
}

// ---- stage 2: logits[b] = left[b] @ right[b]^T + bias ----------------------
// Per batch: C[512,512] f32 = A[512,256] x Bt[512,256], both bf16 K-contig.
// 64x128 tile, BK=64, single-buffer 24KB, swizzled. 1024 blocks (4/CU).
__global__ __launch_bounds__(256, 4) void score_gemm(
    const __bf16* __restrict__ left,
    const __bf16* __restrict__ right,
    const float* __restrict__ biasp,
    float* __restrict__ out) {
  const int nt = blockIdx.x;  // 0..3
  const int mt = blockIdx.y;  // 0..7
  const int bz = blockIdx.z;  // 0..31
  const __bf16* A = left + (size_t)bz * Ss * Rr;
  const __bf16* B = right + (size_t)bz * Ss * Rr;
  float* O = out + (size_t)bz * Ss * Ss;
  const int m0 = mt * 64, n0 = nt * 128;

  __shared__ __align__(16) char smem[24576];
  // A bf16 [64][64] @ 0 (8KB), B bf16 [128][64] @ 8192 (16KB)

  const int t = threadIdx.x;
  const int lane = t & 63;
  const int wave = t >> 6;
  const int wr = wave >> 1, wc = wave & 1;

  f32x4 acc[2][4] = {};

  for (int it = 0; it < 4; ++it) {
    const int k0 = it * 64;
    __syncthreads();
#pragma unroll
    for (int q = 0; q < 2; ++q) {  // A: 512 granules
      int e = q * 256 + t;
      int row = e >> 3, g = e & 7;
      int gsrc = g ^ (row & 7);
      gload_lds16(A + (size_t)(m0 + row) * Rr + k0 + gsrc * 8, smem + e * 16);
    }
#pragma unroll
    for (int q = 0; q < 4; ++q) {  // B: 1024 granules
      int e = q * 256 + t;
      int row = e >> 3, g = e & 7;
      int gsrc = g ^ (row & 7);
      gload_lds16(B + (size_t)(n0 + row) * Rr + k0 + gsrc * 8,
                  smem + 8192 + e * 16);
    }
    __syncthreads();

#pragma unroll
    for (int kk = 0; kk < 2; ++kk) {
      bf16x8 a[2], b[4];
#pragma unroll
      for (int m = 0; m < 2; ++m) {
        int row = wr * 32 + m * 16 + (lane & 15);
        int g = kk * 4 + (lane >> 4);
        a[m] = *(const bf16x8*)(smem + (row * 8 + (g ^ (row & 7))) * 16);
      }
#pragma unroll
      for (int n = 0; n < 4; ++n) {
        int row = wc * 64 + n * 16 + (lane & 15);
        int g = kk * 4 + (lane >> 4);
        b[n] = *(const bf16x8*)(smem + 8192 +
                                (row * 8 + (g ^ (row & 7))) * 16);
      }
#pragma unroll
      for (int m = 0; m < 2; ++m)
#pragma unroll
        for (int n = 0; n < 4; ++n)
          acc[m][n] = __builtin_amdgcn_mfma_f32_16x16x32_bf16(a[m], b[n],
                                                              acc[m][n], 0, 0, 0);
    }
  }

  const float bias = *biasp;
  const int col = lane & 15, rgrp = lane >> 4;
#pragma unroll
  for (int m = 0; m < 2; ++m) {
    int r0 = m0 + wr * 32 + m * 16 + rgrp * 4;
#pragma unroll
    for (int n = 0; n < 4; ++n) {
      int c = n0 + wc * 64 + n * 16 + col;
#pragma unroll
      for (int i = 0; i < 4; ++i)
        O[(size_t)(r0 + i) * Ss + c] = acc[m][n][i] + bias;
    }
  }
}

extern "C" void kernel_launch(void* const* d_in, const int* in_sizes, int n_in,
                              void* d_out, int out_size, void* d_ws,
                              size_t ws_size, hipStream_t stream) {
  const float* batch = (const float*)d_in[0];  // [32][512][1024]
  const float* projL = (const float*)d_in[1];  // [1024][256]
  const float* projR = (const float*)d_in[2];  // [256][1024]
  const float* bias = (const float*)d_in[3];   // [1]
  float* out = (float*)d_out;                  // [32][512][512]

  char* ws = (char*)d_ws;
  __bf16* left = (__bf16*)(ws);                 // 8,388,608 B [16384][256]
  __bf16* right = (__bf16*)(ws + 8388608);      // 8,388,608 B [16384][256]
  __bf16* Btc = (__bf16*)(ws + 16777216);       // 1,048,576 B [512][1024]

  prep_kernel<<<dim3(2048), dim3(256), 0, stream>>>(projL, projR, Btc);
  proj_gemm<<<dim3(256), dim3(512), 0, stream>>>(batch, Btc, left, right);
  score_gemm<<<dim3(4, 8, 32), dim3(256), 0, stream>>>(left, right, bias, out);
}